// Round 17
// baseline (591.178 us; speedup 1.0000x reference)
//
#include <hip/hip_runtime.h>

#define NU 200000
#define NI 200000
#define NN 400000          // NU + NI (unified node space: users 0..NU-1, items NU..NN-1)
#define H 64
#define NE 4000000
#define NP 100000
#define EPSF 1e-5f

#define BSH 9              // nodes per bucket = 512
#define BNODES 512
#define NB ((NN + BNODES - 1) / BNODES)   // 782 buckets (782*512 = 400384 > NN!)
#define NG (NB * 32)       // padded group count (25024; real groups = 25000)
#define CAP_STG 15104      // per-bucket staging capacity (real entries; mean 10240, sigma ~101)
#define CAP_ADJ 18432      // per-bucket padded adj capacity (mean ~15360, sigma ~235 -> ~13 sigma)

#define PBLOCKS 512                          // partition blocks
#define EPB 7816                             // edges per block slice (mult of 8)

#define DUMMY 200000       // padded-slot neighbor id -> zeroed row in each table
#define NROW 200002        // table rows per slot (200000 real + zero row + align)

#define CVTB ((2 * (NU * H / 4) + 255) / 256)   // 25000 cvt blocks
#define WCVTB 128                                // wcvt blocks

typedef unsigned short u16;
typedef __attribute__((ext_vector_type(8))) short bf16x8;
typedef __attribute__((ext_vector_type(4))) float f32x4;

__device__ __forceinline__ u16 f2bf(float f) {
    unsigned int b = __float_as_uint(f);
    b += 0x7FFFu + ((b >> 16) & 1u);     // round-to-nearest-even
    return (u16)(b >> 16);
}

// ================= prep: part1 histogram + bf16 cvt + weight prep (one dispatch)
__global__ __launch_bounds__(256) void prep_kernel(
    const int* __restrict__ src, const int* __restrict__ dst,
    int* __restrict__ blkhist,
    const float4* __restrict__ inU, const float4* __restrict__ inI,
    ushort4* __restrict__ outU, ushort4* __restrict__ outI,
    u16* __restrict__ f1,
    const float* __restrict__ u_ll_w, const float* __restrict__ u_lr_w,
    const float* __restrict__ i_ll_w, const float* __restrict__ i_lr_w,
    const float* __restrict__ u_ll_b, const float* __restrict__ i_ll_b,
    const float* __restrict__ u_g, const float* __restrict__ u_b,
    const float* __restrict__ u_m, const float* __restrict__ u_v,
    const float* __restrict__ i_g, const float* __restrict__ i_b,
    const float* __restrict__ i_m, const float* __restrict__ i_v,
    u16* __restrict__ wcat, float* __restrict__ scsh)
{
    int bid = blockIdx.x, tid = threadIdx.x;
    if (bid < PBLOCKS) {
        // ---- part1: per-(bucket, block) entry counts ----
        __shared__ int hist[NB];
        for (int i = tid; i < NB; i += 256) hist[i] = 0;
        __syncthreads();
        int e0 = bid * EPB, e1 = min(NE, e0 + EPB);
        for (int e = e0 + tid * 4; e + 4 <= e1; e += 1024) {
            int4 s4 = *(const int4*)&src[e];
            int4 d4 = *(const int4*)&dst[e];
            atomicAdd(&hist[s4.x >> BSH], 1); atomicAdd(&hist[(NU + d4.x) >> BSH], 1);
            atomicAdd(&hist[s4.y >> BSH], 1); atomicAdd(&hist[(NU + d4.y) >> BSH], 1);
            atomicAdd(&hist[s4.z >> BSH], 1); atomicAdd(&hist[(NU + d4.z) >> BSH], 1);
            atomicAdd(&hist[s4.w >> BSH], 1); atomicAdd(&hist[(NU + d4.w) >> BSH], 1);
        }
        __syncthreads();
        for (int i = tid; i < NB; i += 256)
            blkhist[(size_t)i * PBLOCKS + bid] = hist[i];
    } else if (bid < PBLOCKS + CVTB) {
        // ---- cvt: f32 -> bf16 tables; block 0 also zeroes DUMMY rows 0,1,4,5 ----
        int cb = bid - PBLOCKS;
        if (cb == 0 && tid < 128) {
            const int sl[4] = {0, 1, 4, 5};
            int s = sl[tid >> 5], wd = tid & 31;
            unsigned int* p = (unsigned int*)(f1 + (size_t)s * NROW * H + (size_t)DUMMY * H);
            p[wd] = 0u;
        }
        const int n4 = NU * H / 4;
        int i = cb * 256 + tid;
        const float4* in;
        ushort4* out;
        if (i < n4) { in = inU; out = outU; }
        else        { in = inI; out = outI; i -= n4; if (i >= n4) return; }
        float4 v = in[i];
        ushort4 h;
        h.x = f2bf(v.x); h.y = f2bf(v.y); h.z = f2bf(v.z); h.w = f2bf(v.w);
        out[i] = h;
    } else {
        // ---- wcvt: stacked transposed bf16 weights + BN fold ----
        int idx = (bid - PBLOCKS - CVTB) * 256 + tid;
        if (idx < 32768) {
            int k = idx & 127, f = (idx >> 7) & 63, t = (idx >> 13) & 1, l = idx >> 14;
            const float* W = t ? (k < 64 ? i_ll_w : i_lr_w)
                               : (k < 64 ? u_ll_w : u_lr_w);
            wcat[idx] = f2bf(W[l * 4096 + (k & 63) * 64 + f]);
        }
        if (idx < 512) {
            int j = idx & 63, half = (idx >> 6) & 1, t = (idx >> 7) & 1, l = idx >> 8;
            const float *g = t ? i_g : u_g, *b = t ? i_b : u_b;
            const float *m = t ? i_m : u_m, *v = t ? i_v : u_v;
            const float *bl = t ? i_ll_b : u_ll_b;
            float sc = g[l * 64 + j] * rsqrtf(v[l * 64 + j] + EPSF);
            scsh[idx] = half ? (bl[l * 64 + j] - m[l * 64 + j]) * sc + b[l * 64 + j]
                             : sc;
        }
    }
}

// per-bucket exclusive scan over its PBLOCKS counts (in place); totals -> g_bcnt
__global__ __launch_bounds__(256) void colscan_kernel(
    int* __restrict__ blkhist, int* __restrict__ g_bcnt)
{
    __shared__ int s[256];
    int b = blockIdx.x, tid = threadIdx.x;
    int* col = blkhist + (size_t)b * PBLOCKS;
    int v0 = col[2 * tid], v1 = col[2 * tid + 1];
    int ps = v0 + v1;
    s[tid] = ps;
    __syncthreads();
    for (int d = 1; d < 256; d <<= 1) {
        int t = (tid >= d) ? s[tid - d] : 0;
        __syncthreads();
        s[tid] += t;
        __syncthreads();
    }
    int ex = s[tid] - ps;   // exclusive over pairs
    col[2 * tid] = ex;
    col[2 * tid + 1] = ex + v0;
    if (tid == 255) g_bcnt[b] = s[255];
}

// entry = (local_node << 18) | neighbor   (local<512 -> 9 bits, nbr<200000 -> 18 bits)
__global__ __launch_bounds__(256) void part2_kernel(
    const int* __restrict__ src, const int* __restrict__ dst,
    const int* __restrict__ blkhist, int* __restrict__ staging)
{
    __shared__ int cur[NB];
    int tid = threadIdx.x, blk = blockIdx.x;
    for (int i = tid; i < NB; i += 256)
        cur[i] = i * CAP_STG + blkhist[(size_t)i * PBLOCKS + blk];
    __syncthreads();
    int e0 = blk * EPB, e1 = min(NE, e0 + EPB);
    for (int e = e0 + tid * 4; e + 4 <= e1; e += 1024) {
        int4 s4 = *(const int4*)&src[e];
        int4 d4 = *(const int4*)&dst[e];
        int sv[4] = {s4.x, s4.y, s4.z, s4.w};
        int dv[4] = {d4.x, d4.y, d4.z, d4.w};
#pragma unroll
        for (int q = 0; q < 4; ++q) {
            int s = sv[q], d = dv[q];
            int p1 = atomicAdd(&cur[s >> BSH], 1);
            staging[p1] = ((s & (BNODES - 1)) << 18) | d;
            int gn = NU + d;
            int p2 = atomicAdd(&cur[gn >> BSH], 1);
            staging[p2] = ((gn & (BNODES - 1)) << 18) | s;
        }
    }
}

// Per-bucket fill into group16-max-padded INTERLEAVED adj:
//   group gamma (16 nodes) at gbase; id for (node n, step k) at gbase + k*16 + (n&15).
//   All 16 nodes of a group share padded length Lg (mult of 4); pads = DUMMY<<7.
//   adj holds BYTE offsets (id*128) into the 128-B-row tables.
// deg is sized NB*BNODES and goff/glen NB*32 so tail-bucket writes are in-bounds.
__global__ __launch_bounds__(256) void bucket_fill_kernel(
    const int* __restrict__ g_bcnt, const int* __restrict__ staging,
    int* __restrict__ goff, int* __restrict__ glen,
    int* __restrict__ deg, int* __restrict__ adj)
{
    __shared__ int hist[BNODES];     // counts, then per-node cursors
    __shared__ int gmax[32];         // per-group max count -> Lg
    __shared__ int gbase_s[33];
    __shared__ int adj_st[CAP_ADJ];
    int tid = threadIdx.x;
    int b = blockIdx.x;
    int e0 = b * CAP_STG;
    int cnt = g_bcnt[b];
    int node_base = b * BNODES;

    for (int i = tid; i < CAP_ADJ; i += 256) adj_st[i] = DUMMY << 7;
    hist[tid] = 0; hist[tid + 256] = 0;
    if (tid < 32) gmax[tid] = 0;
    __syncthreads();
    for (int i = tid; i < cnt; i += 256)
        atomicAdd(&hist[staging[e0 + i] >> 18], 1);
    __syncthreads();

    int h0 = hist[2 * tid], h1 = hist[2 * tid + 1];
    atomicMax(&gmax[tid >> 3], max(h0, h1));
    deg[node_base + 2 * tid]     = h0;   // deg sized NB*BNODES: in-bounds for all b
    deg[node_base + 2 * tid + 1] = h1;
    __syncthreads();
    if (tid == 0) {
        int acc = 0;
#pragma unroll
        for (int gma = 0; gma < 32; ++gma) {
            gbase_s[gma] = acc;
            int L = (gmax[gma] + 3) & ~3;
            gmax[gma] = L;            // now holds Lg
            acc += 16 * L;
        }
        gbase_s[32] = acc;
    }
    __syncthreads();
    if (tid < 32) {
        int gb = gbase_s[tid];
        int L = gmax[tid];
        // statistically unreachable clamp: never let a group's region leave the bucket
        int avail = max(0, (CAP_ADJ - gb) / 16) & ~3;
        L = min(L, avail);
        goff[b * 32 + tid] = b * CAP_ADJ + gb;   // goff/glen sized NB*32: in-bounds
        glen[b * 32 + tid] = L;
    }
    hist[2 * tid] = 0; hist[2 * tid + 1] = 0;   // cursors
    __syncthreads();

    for (int i = tid; i < cnt; i += 256) {
        int v = staging[e0 + i];
        int nl = v >> 18;
        int p = atomicAdd(&hist[nl], 1);
        int pos = gbase_s[nl >> 4] + p * 16 + (nl & 15);
        if (pos < CAP_ADJ) adj_st[pos] = (v & 0x3FFFF) << 7;   // byte offset
    }
    __syncthreads();
    int ptotal = min(gbase_s[32], CAP_ADJ);
    for (int i = tid; i < ptotal; i += 256)
        adj[(size_t)b * CAP_ADJ + i] = adj_st[i];
}

// ================= fused pull + MFMA update ====================================
// One wave owns 16 nodes (= one group). Phase 1: row-parallel gather — lane l
// owns nodes (l&7) and 8|(l&7) with fixed 8-feat slice (l>>3)*8; each dwordx4
// load covers 8 full rows (8 independent streams); 8 loads per 4-step chunk +
// coalesced interleaved id loads -> ~8 KB in flight/wave, no clamps, no
// cross-lane reduction. Phase 2: 16-node x 64-feat MFMA update. No barriers.
__global__ __launch_bounds__(256) void pull_update_kernel(
    const int* __restrict__ goff, const int* __restrict__ glen,
    const int* __restrict__ deg, const int* __restrict__ adj,
    const u16* __restrict__ xu16, const u16* __restrict__ xi16,   // gather tables
    const u16* __restrict__ selfU, const u16* __restrict__ selfI, // self-path rows
    u16* __restrict__ outU, u16* __restrict__ outI,
    const u16* __restrict__ wcat,    // this layer: [2 types][64 feat][128 k]
    const float* __restrict__ scsh)  // this layer: [2 types][2][64]
{
    __shared__ u16 sAgg[4][16][72];
    int tid = threadIdx.x;
    int wave = tid >> 6, lane = tid & 63;
    int gw = blockIdx.x * 4 + wave;            // global group id (16 nodes)
    bool isU = gw < (NU / 16);
    int node0 = (isU ? gw : gw - NU / 16) * 16;
    const u16* table = isU ? xi16 : xu16;      // gather the OPPOSITE type
    const u16* selfx = isU ? selfU : selfI;
    u16* out         = isU ? outU : outI;
    const u16* wt      = wcat + (isU ? 0 : 64 * 128);
    const float* sc_p  = scsh + (isU ? 0 : 128);
    const float* sh_p  = sc_p + 64;
    int wbase = gw * 16;                       // unified node index base

    // hoist self-path loads: in flight during the whole gather phase
    int row = lane & 15, g = lane >> 4;
    const u16* xrow = selfx + (size_t)(node0 + row) * H + g * 8;
    bf16x8 sa2 = *(const bf16x8*)(xrow);
    bf16x8 sa3 = *(const bf16x8*)(xrow + 32);

    int degv = (lane < 16) ? deg[wbase + lane] : 0;
    int gbase = goff[gw];
    int Lg    = glen[gw];

    int na = lane & 7;                 // node slot (nodes na and 8|na)
    int fo = (lane >> 3) * 8;          // owned feature slice
    unsigned laneoff = (unsigned)fo * 2u;
    const char* tb = (const char*)table;
    const int* ap = adj + gbase + lane;

    float accA[8] = {0,0,0,0,0,0,0,0};
    float accB[8] = {0,0,0,0,0,0,0,0};

#define ACC8(acc, wv) \
    acc[0] += __uint_as_float((wv).x << 16); acc[1] += __uint_as_float((wv).x & 0xFFFF0000u); \
    acc[2] += __uint_as_float((wv).y << 16); acc[3] += __uint_as_float((wv).y & 0xFFFF0000u); \
    acc[4] += __uint_as_float((wv).z << 16); acc[5] += __uint_as_float((wv).z & 0xFFFF0000u); \
    acc[6] += __uint_as_float((wv).w << 16); acc[7] += __uint_as_float((wv).w & 0xFFFF0000u);

    if (Lg > 0) {
        int idv = ap[0];   // ids for step k0 + (lane>>4), node lane&15 (byte offsets)
        for (int k0 = 0; ; ) {
            int nxt = k0 + 4;
            int idn;
            if (nxt < Lg) idn = ap[nxt * 16];
            uint4 w[8];
#pragma unroll
            for (int s = 0; s < 4; ++s) {
                unsigned oa = (unsigned)__shfl(idv, s * 16 + na) + laneoff;
                unsigned ob = (unsigned)__shfl(idv, s * 16 + 8 + na) + laneoff;
                w[2 * s]     = *(const uint4*)(tb + oa);
                w[2 * s + 1] = *(const uint4*)(tb + ob);
            }
#pragma unroll
            for (int s = 0; s < 4; ++s) {
                ACC8(accA, w[2 * s])
                ACC8(accB, w[2 * s + 1])
            }
            if (nxt >= Lg) break;
            idv = idn; k0 = nxt;
        }
    }
#undef ACC8

    // scale by 1/deg, pack to bf16, write own (node, feat-slice) cells
    int dgA = __shfl(degv, na);
    int dgB = __shfl(degv, 8 + na);
    float invA = 1.0f / fmaxf((float)dgA, 1.0f);
    float invB = 1.0f / fmaxf((float)dgB, 1.0f);
    uint4 pka, pkb;
    pka.x = ((unsigned)f2bf(accA[1] * invA) << 16) | f2bf(accA[0] * invA);
    pka.y = ((unsigned)f2bf(accA[3] * invA) << 16) | f2bf(accA[2] * invA);
    pka.z = ((unsigned)f2bf(accA[5] * invA) << 16) | f2bf(accA[4] * invA);
    pka.w = ((unsigned)f2bf(accA[7] * invA) << 16) | f2bf(accA[6] * invA);
    pkb.x = ((unsigned)f2bf(accB[1] * invB) << 16) | f2bf(accB[0] * invB);
    pkb.y = ((unsigned)f2bf(accB[3] * invB) << 16) | f2bf(accB[2] * invB);
    pkb.z = ((unsigned)f2bf(accB[5] * invB) << 16) | f2bf(accB[4] * invB);
    pkb.w = ((unsigned)f2bf(accB[7] * invB) << 16) | f2bf(accB[6] * invB);
    *(uint4*)&sAgg[wave][na][fo]     = pka;
    *(uint4*)&sAgg[wave][8 + na][fo] = pkb;
    // no __syncthreads: each wave reads only its own sAgg tile

    // ---- phase 2: MFMA update of the same 16 nodes ----
    bf16x8 a[4];
    a[0] = *(const bf16x8*)&sAgg[wave][row][g * 8];
    a[1] = *(const bf16x8*)&sAgg[wave][row][32 + g * 8];
    a[2] = sa2;
    a[3] = sa3;

#pragma unroll
    for (int ct = 0; ct < 4; ++ct) {
        int feat = ct * 16 + row;
        const u16* wrow = wt + feat * 128 + g * 8;
        f32x4 acc = {0.f, 0.f, 0.f, 0.f};
#pragma unroll
        for (int kb = 0; kb < 4; ++kb) {
            bf16x8 b = *(const bf16x8*)(wrow + kb * 32);
            acc = __builtin_amdgcn_mfma_f32_16x16x32_bf16(a[kb], b, acc, 0, 0, 0);
        }
        float s = sc_p[feat], h = sh_p[feat];
#pragma unroll
        for (int r = 0; r < 4; ++r) {
            int node = node0 + g * 4 + r;   // D: col=lane&15, row=(lane>>4)*4+r
            float v = fmaxf(acc[r] * s + h, 0.f);
            out[(size_t)node * H + feat] = f2bf(v);
        }
    }
}

// ================= MLP head (register-tiled fc1, LDS fc2, bf16 gathers) ========
__global__ __launch_bounds__(256) void mlp_kernel(
    const int* __restrict__ eli,
    const u16* __restrict__ xu16, const u16* __restrict__ xi16,
    const float* __restrict__ fc1w, const float* __restrict__ fc1b,
    const float* __restrict__ fc2w, const float* __restrict__ fc2b,
    float* __restrict__ out, int n)
{
    __shared__ float sW[32][68];
    __shared__ float sA[64][36];
    __shared__ float sH[64][68];
    __shared__ int   sid[128];
    __shared__ float sW2[256];
    int tid = threadIdx.x;
    int p0 = blockIdx.x * 64;
    if (tid < 128) {
        int p = p0 + (tid & 63);
        int side = tid >> 6;
        sid[tid] = (p < n) ? eli[side * NP + p] : -1;
    }
    sW2[tid] = fc2w[tid];
    __syncthreads();

    int jt = (tid & 15) * 4;
    int pt = (tid >> 4) * 4;
    float4 b4 = *(const float4*)&fc1b[jt];
    float acc[4][4];
#pragma unroll
    for (int i = 0; i < 4; ++i) {
        acc[i][0] = b4.x; acc[i][1] = b4.y; acc[i][2] = b4.z; acc[i][3] = b4.w;
    }

    for (int ch = 0; ch < 4; ++ch) {
        int k0 = ch * 32;
        const u16* tab = (ch < 2) ? xu16 : xi16;
        int idbase = (ch < 2) ? 0 : 64;
        int koff = (ch & 1) * 32;
        for (int idx = tid; idx < 64 * 16; idx += 256) {
            int r = idx >> 4, cp = idx & 15;
            int id = sid[idbase + r];
            unsigned int wv = (id >= 0)
                ? *(const unsigned int*)&tab[(size_t)id * H + koff + cp * 2] : 0u;
            sA[r][cp * 2]     = __uint_as_float(wv << 16);
            sA[r][cp * 2 + 1] = __uint_as_float(wv & 0xFFFF0000u);
        }
        for (int idx = tid; idx < 32 * 64; idx += 256) {
            int kk = idx >> 6, j = idx & 63;
            sW[kk][j] = fc1w[(k0 + kk) * 64 + j];
        }
        __syncthreads();
        for (int kk = 0; kk < 32; kk += 4) {
            float a[4][4];
#pragma unroll
            for (int i = 0; i < 4; ++i) {
                float4 t = *(const float4*)&sA[pt + i][kk];
                a[i][0] = t.x; a[i][1] = t.y; a[i][2] = t.z; a[i][3] = t.w;
            }
#pragma unroll
            for (int q = 0; q < 4; ++q) {
                float4 w = *(const float4*)&sW[kk + q][jt];
                float wv[4] = {w.x, w.y, w.z, w.w};
#pragma unroll
                for (int i = 0; i < 4; ++i)
#pragma unroll
                    for (int j = 0; j < 4; ++j)
                        acc[i][j] += a[i][q] * wv[j];
            }
        }
        __syncthreads();
    }

#pragma unroll
    for (int i = 0; i < 4; ++i)
#pragma unroll
        for (int j = 0; j < 4; ++j)
            sH[pt + i][jt + j] = fmaxf(acc[i][j], 0.f);
    __syncthreads();

    int pp = tid >> 2, c = tid & 3;
    float o = 0.f;
#pragma unroll
    for (int j = 0; j < 64; ++j) o += sH[pp][j] * sW2[j * 4 + c];
    int p = p0 + pp;
    if (p < n) out[(size_t)p * 4 + c] = o + fc2b[c];
}

extern "C" void kernel_launch(void* const* d_in, const int* in_sizes, int n_in,
                              void* d_out, int out_size, void* d_ws, size_t ws_size,
                              hipStream_t stream) {
    const int*   edge_index = (const int*)d_in[0];
    const int*   eli        = (const int*)d_in[1];
    const float* user_emb   = (const float*)d_in[2];
    const float* item_emb   = (const float*)d_in[3];
    const float* u_ll_w     = (const float*)d_in[4];
    const float* u_ll_b     = (const float*)d_in[5];
    const float* u_lr_w     = (const float*)d_in[6];
    const float* i_ll_w     = (const float*)d_in[7];
    const float* i_ll_b     = (const float*)d_in[8];
    const float* i_lr_w     = (const float*)d_in[9];
    const float* u_bn_g     = (const float*)d_in[10];
    const float* u_bn_b     = (const float*)d_in[11];
    const float* u_bn_m     = (const float*)d_in[12];
    const float* u_bn_v     = (const float*)d_in[13];
    const float* i_bn_g     = (const float*)d_in[14];
    const float* i_bn_b     = (const float*)d_in[15];
    const float* i_bn_m     = (const float*)d_in[16];
    const float* i_bn_v     = (const float*)d_in[17];
    const float* fc1_w      = (const float*)d_in[18];
    const float* fc1_b      = (const float*)d_in[19];
    const float* fc2_w      = (const float*)d_in[20];
    const float* fc2_b      = (const float*)d_in[21];
    float* out = (float*)d_out;

    const int* src = edge_index;
    const int* dst = edge_index + NE;

    // ---- workspace: 6 slots x 25.6 MB + adj 57.7 MB + deg/goff/glen ~1.8 MB
    //      ≈ 213 MB (238 MB is the proven-safe ceiling) ----
    const size_t S = (size_t)NROW * H;   // elems per slot (incl. zero row)
    char* w = (char*)d_ws;
    u16* f1 = (u16*)w;          w += 6 * S * 2;
    int* adj    = (int*)w;      w += ((size_t)NB * CAP_ADJ + 128) * 4;
    int* deg    = (int*)w;      w += (size_t)NB * BNODES * 4;   // bucket-padded (400384)
    int* goff   = (int*)w;      w += (size_t)NG * 4;            // bucket-padded (25024)
    int* glen   = (int*)w;      w += (size_t)NG * 4;
    int* g_bcnt = (int*)w;      w += (size_t)NB * 4;
    u16* wcat   = (u16*)w;      w += (size_t)32768 * 2;   // [2][2][64][128] bf16
    float* scsh = (float*)w;    w += (size_t)512 * 4;     // [2][2][2][64] f32

    // Slot plan:
    //   s0/s1: emb16_u/i (prep -> L0 gather + self) -> fin16_u/i (L1 out -> mlp)
    //   s2/s3: staging (47.25 MB spans both; CSR build only)
    //   s4   : blkhist (1.6 MB head; dead after part2)
    //   s4/s5: xA16_u/i (L0 out; L1 gather + self)
    u16* emb16_u = f1 + 0 * S;
    u16* emb16_i = f1 + 1 * S;
    u16* fin16_u = f1 + 0 * S;
    u16* fin16_i = f1 + 1 * S;
    u16* xA16_u  = f1 + 4 * S;
    u16* xA16_i  = f1 + 5 * S;
    int* staging = (int*)(f1 + 2 * S);
    int* blkhist = (int*)(f1 + 4 * S);

    // ---- prep: part1 + cvt + wcvt in one dispatch ----
    prep_kernel<<<PBLOCKS + CVTB + WCVTB, 256, 0, stream>>>(
        src, dst, blkhist,
        (const float4*)user_emb, (const float4*)item_emb,
        (ushort4*)emb16_u, (ushort4*)emb16_i, f1,
        u_ll_w, u_lr_w, i_ll_w, i_lr_w, u_ll_b, i_ll_b,
        u_bn_g, u_bn_b, u_bn_m, u_bn_v,
        i_bn_g, i_bn_b, i_bn_m, i_bn_v, wcat, scsh);

    // ---- CSR build ----
    colscan_kernel<<<NB, 256, 0, stream>>>(blkhist, g_bcnt);
    part2_kernel<<<PBLOCKS, 256, 0, stream>>>(src, dst, blkhist, staging);
    bucket_fill_kernel<<<NB, 256, 0, stream>>>(g_bcnt, staging, goff, glen, deg, adj);

    const int pu_blocks = (NN / 16) / 4;   // one wave per 16-node group

    // ---- layer 0 (gather + self both from emb16) ----
    pull_update_kernel<<<pu_blocks, 256, 0, stream>>>(
        goff, glen, deg, adj, emb16_u, emb16_i, emb16_u, emb16_i,
        xA16_u, xA16_i, wcat, scsh);

    // ---- layer 1 (gather + self both from xA16) ----
    pull_update_kernel<<<pu_blocks, 256, 0, stream>>>(
        goff, glen, deg, adj, xA16_u, xA16_i, xA16_u, xA16_i,
        fin16_u, fin16_i, wcat + 16384, scsh + 256);

    // ---- MLP head ----
    mlp_kernel<<<(NP + 63) / 64, 256, 0, stream>>>(
        eli, fin16_u, fin16_i, fc1_w, fc1_b, fc2_w, fc2_b, out, NP);
}

// Round 18
// 546.974 us; speedup vs baseline: 1.0808x; 1.0808x over previous
//
#include <hip/hip_runtime.h>

#define NU 200000
#define NI 200000
#define NN 400000          // NU + NI (unified node space: users 0..NU-1, items NU..NN-1)
#define H 64
#define NE 4000000
#define NP 100000
#define EPSF 1e-5f

#define BSH 9              // nodes per bucket = 512
#define BNODES 512
#define NB ((NN + BNODES - 1) / BNODES)   // 782 buckets
#define CAP 15104          // per-bucket staging/adj capacity (padded mean ~13.3k)

#define PBLOCKS 512                          // partition blocks
#define EPB 7816                             // edges per block slice (mult of 8)

#define DUMMY 200000       // padded-slot neighbor id -> zeroed row in each table
#define NROW 200002        // table rows per slot (200000 real + zero row + align)

#define CVTB ((2 * (NU * H / 4) + 255) / 256)   // 25000 cvt blocks
#define WCVTB 128                                // wcvt blocks

typedef unsigned short u16;
typedef __attribute__((ext_vector_type(8))) short bf16x8;
typedef __attribute__((ext_vector_type(4))) float f32x4;

__device__ __forceinline__ u16 f2bf(float f) {
    unsigned int b = __float_as_uint(f);
    b += 0x7FFFu + ((b >> 16) & 1u);     // round-to-nearest-even
    return (u16)(b >> 16);
}

// ================= prep: part1 histogram + bf16 cvt + weight prep (one dispatch)
__global__ __launch_bounds__(256) void prep_kernel(
    const int* __restrict__ src, const int* __restrict__ dst,
    int* __restrict__ blkhist,
    const float4* __restrict__ inU, const float4* __restrict__ inI,
    ushort4* __restrict__ outU, ushort4* __restrict__ outI,
    u16* __restrict__ f1,
    const float* __restrict__ u_ll_w, const float* __restrict__ u_lr_w,
    const float* __restrict__ i_ll_w, const float* __restrict__ i_lr_w,
    const float* __restrict__ u_ll_b, const float* __restrict__ i_ll_b,
    const float* __restrict__ u_g, const float* __restrict__ u_b,
    const float* __restrict__ u_m, const float* __restrict__ u_v,
    const float* __restrict__ i_g, const float* __restrict__ i_b,
    const float* __restrict__ i_m, const float* __restrict__ i_v,
    u16* __restrict__ wcat, float* __restrict__ scsh)
{
    int bid = blockIdx.x, tid = threadIdx.x;
    if (bid < PBLOCKS) {
        // ---- part1: per-(bucket, block) entry counts ----
        __shared__ int hist[NB];
        for (int i = tid; i < NB; i += 256) hist[i] = 0;
        __syncthreads();
        int e0 = bid * EPB, e1 = min(NE, e0 + EPB);
        for (int e = e0 + tid * 4; e + 4 <= e1; e += 1024) {
            int4 s4 = *(const int4*)&src[e];
            int4 d4 = *(const int4*)&dst[e];
            atomicAdd(&hist[s4.x >> BSH], 1); atomicAdd(&hist[(NU + d4.x) >> BSH], 1);
            atomicAdd(&hist[s4.y >> BSH], 1); atomicAdd(&hist[(NU + d4.y) >> BSH], 1);
            atomicAdd(&hist[s4.z >> BSH], 1); atomicAdd(&hist[(NU + d4.z) >> BSH], 1);
            atomicAdd(&hist[s4.w >> BSH], 1); atomicAdd(&hist[(NU + d4.w) >> BSH], 1);
        }
        __syncthreads();
        for (int i = tid; i < NB; i += 256)
            blkhist[(size_t)i * PBLOCKS + bid] = hist[i];
    } else if (bid < PBLOCKS + CVTB) {
        // ---- cvt: f32 -> bf16 tables; block 0 also zeroes DUMMY rows 0,1,4,5 ----
        int cb = bid - PBLOCKS;
        if (cb == 0 && tid < 128) {
            const int sl[4] = {0, 1, 4, 5};
            int s = sl[tid >> 5], wd = tid & 31;
            unsigned int* p = (unsigned int*)(f1 + (size_t)s * NROW * H + (size_t)DUMMY * H);
            p[wd] = 0u;
        }
        const int n4 = NU * H / 4;
        int i = cb * 256 + tid;
        const float4* in;
        ushort4* out;
        if (i < n4) { in = inU; out = outU; }
        else        { in = inI; out = outI; i -= n4; if (i >= n4) return; }
        float4 v = in[i];
        ushort4 h;
        h.x = f2bf(v.x); h.y = f2bf(v.y); h.z = f2bf(v.z); h.w = f2bf(v.w);
        out[i] = h;
    } else {
        // ---- wcvt: stacked transposed bf16 weights + BN fold ----
        int idx = (bid - PBLOCKS - CVTB) * 256 + tid;
        if (idx < 32768) {
            int k = idx & 127, f = (idx >> 7) & 63, t = (idx >> 13) & 1, l = idx >> 14;
            const float* W = t ? (k < 64 ? i_ll_w : i_lr_w)
                               : (k < 64 ? u_ll_w : u_lr_w);
            wcat[idx] = f2bf(W[l * 4096 + (k & 63) * 64 + f]);
        }
        if (idx < 512) {
            int j = idx & 63, half = (idx >> 6) & 1, t = (idx >> 7) & 1, l = idx >> 8;
            const float *g = t ? i_g : u_g, *b = t ? i_b : u_b;
            const float *m = t ? i_m : u_m, *v = t ? i_v : u_v;
            const float *bl = t ? i_ll_b : u_ll_b;
            float sc = g[l * 64 + j] * rsqrtf(v[l * 64 + j] + EPSF);
            scsh[idx] = half ? (bl[l * 64 + j] - m[l * 64 + j]) * sc + b[l * 64 + j]
                             : sc;
        }
    }
}

// per-bucket exclusive scan over its PBLOCKS counts (in place); totals -> g_bcnt
__global__ __launch_bounds__(256) void colscan_kernel(
    int* __restrict__ blkhist, int* __restrict__ g_bcnt)
{
    __shared__ int s[256];
    int b = blockIdx.x, tid = threadIdx.x;
    int* col = blkhist + (size_t)b * PBLOCKS;
    int v0 = col[2 * tid], v1 = col[2 * tid + 1];
    int ps = v0 + v1;
    s[tid] = ps;
    __syncthreads();
    for (int d = 1; d < 256; d <<= 1) {
        int t = (tid >= d) ? s[tid - d] : 0;
        __syncthreads();
        s[tid] += t;
        __syncthreads();
    }
    int ex = s[tid] - ps;   // exclusive over pairs
    col[2 * tid] = ex;
    col[2 * tid + 1] = ex + v0;
    if (tid == 255) g_bcnt[b] = s[255];
}

// entry = (local_node << 18) | neighbor   (local<512 -> 9 bits, nbr<200000 -> 18 bits)
__global__ __launch_bounds__(256) void part2_kernel(
    const int* __restrict__ src, const int* __restrict__ dst,
    const int* __restrict__ blkhist, int* __restrict__ staging)
{
    __shared__ int cur[NB];
    int tid = threadIdx.x, blk = blockIdx.x;
    for (int i = tid; i < NB; i += 256)
        cur[i] = i * CAP + blkhist[(size_t)i * PBLOCKS + blk];
    __syncthreads();
    int e0 = blk * EPB, e1 = min(NE, e0 + EPB);
    for (int e = e0 + tid * 4; e + 4 <= e1; e += 1024) {
        int4 s4 = *(const int4*)&src[e];
        int4 d4 = *(const int4*)&dst[e];
        int sv[4] = {s4.x, s4.y, s4.z, s4.w};
        int dv[4] = {d4.x, d4.y, d4.z, d4.w};
#pragma unroll
        for (int q = 0; q < 4; ++q) {
            int s = sv[q], d = dv[q];
            int p1 = atomicAdd(&cur[s >> BSH], 1);
            staging[p1] = ((s & (BNODES - 1)) << 18) | d;
            int gn = NU + d;
            int p2 = atomicAdd(&cur[gn >> BSH], 1);
            staging[p2] = ((gn & (BNODES - 1)) << 18) | s;
        }
    }
}

// Per-bucket fill into pair-max-padded fixed-capacity adj: adj[b*CAP + i].
// Nodes (2t, 2t+1) are padded to the SAME 8-multiple length (max of the two);
// adj holds BYTE offsets (id*128) into the 128-B-row tables; pads -> DUMMY<<7.
__global__ __launch_bounds__(256) void bucket_fill_kernel(
    const int* __restrict__ g_bcnt, const int* __restrict__ staging,
    int* __restrict__ off, int* __restrict__ deg, int* __restrict__ adj)
{
    __shared__ int hist[BNODES];     // counts -> exclusive slot offsets (cursors)
    __shared__ int psum[256];
    __shared__ int adj_st[CAP];
    int tid = threadIdx.x;
    int b = blockIdx.x;
    int e0 = b * CAP;
    int cnt = g_bcnt[b];
    int node_base = b * BNODES;

    for (int i = tid; i < CAP; i += 256) adj_st[i] = DUMMY << 7;   // pad prefill
    hist[tid] = 0; hist[tid + 256] = 0;
    __syncthreads();
    for (int i = tid; i < cnt; i += 256)
        atomicAdd(&hist[staging[e0 + i] >> 18], 1);
    __syncthreads();

    int h0 = hist[2 * tid], h1 = hist[2 * tid + 1];
    int hp = max((h0 + 7) & ~7, (h1 + 7) & ~7);   // pair-max padded length
    psum[tid] = 2 * hp;
    __syncthreads();
    for (int d = 1; d < 256; d <<= 1) {
        int t = (tid >= d) ? psum[tid - d] : 0;
        __syncthreads();
        psum[tid] += t;
        __syncthreads();
    }
    int ex0 = psum[tid] - 2 * hp;
    int ex1 = ex0 + hp;
    int n0 = node_base + 2 * tid;
    if (n0 < NN)     { off[n0]     = e0 + ex0; deg[n0]     = h0; }
    if (n0 + 1 < NN) { off[n0 + 1] = e0 + ex1; deg[n0 + 1] = h1; }
    __syncthreads();
    hist[2 * tid] = ex0; hist[2 * tid + 1] = ex1;   // reuse as cursors
    __syncthreads();

    int ptotal = min(psum[255], CAP);   // statistically always < CAP

    for (int i = tid; i < cnt; i += 256) {
        int v = staging[e0 + i];
        int p = atomicAdd(&hist[v >> 18], 1);
        if (p < CAP) adj_st[p] = (v & 0x3FFFF) << 7;   // byte offset
    }
    __syncthreads();
    for (int i = tid; i < ptotal; i += 256)
        adj[(size_t)b * CAP + i] = adj_st[i];
}

// ================= fused pull + MFMA update ====================================
// One wave owns 16 nodes as 8 PAIRS: lanes 0-31 gather node 2p, lanes 32-63
// node 2p+1 (2 rows x 16 lanes). Pair-max padding -> no per-load clamps; adj
// holds byte offsets -> saddr loads. 2-deep pipeline, 4 loads per step.
__global__ __launch_bounds__(256) void pull_update_kernel(
    const int* __restrict__ off, const int* __restrict__ deg,
    const int* __restrict__ adj,
    const u16* __restrict__ xu16, const u16* __restrict__ xi16,   // gather tables
    const u16* __restrict__ selfU, const u16* __restrict__ selfI, // self-path rows
    u16* __restrict__ outU, u16* __restrict__ outI,
    const u16* __restrict__ wcat,    // this layer: [2 types][64 feat][128 k]
    const float* __restrict__ scsh)  // this layer: [2 types][2][64]
{
    __shared__ u16 sAgg[4][16][72];
    int tid = threadIdx.x;
    int wave = tid >> 6, lane = tid & 63;
    int gw = blockIdx.x * 4 + wave;            // global wave id, one per 16 nodes
    bool isU = gw < (NU / 16);
    int node0 = (isU ? gw : gw - NU / 16) * 16;
    const u16* table = isU ? xi16 : xu16;      // gather the OPPOSITE type
    const u16* selfx = isU ? selfU : selfI;
    u16* out         = isU ? outU : outI;
    const u16* wt      = wcat + (isU ? 0 : 64 * 128);
    const float* sc_p  = scsh + (isU ? 0 : 128);
    const float* sh_p  = sc_p + 64;
    int wbase = isU ? node0 : NU + node0;      // unified off/deg index

    // hoist self-path loads: in flight during the whole gather phase
    int row = lane & 15, g = lane >> 4;
    const u16* xrow = selfx + (size_t)(node0 + row) * H + g * 8;
    bf16x8 sa2 = *(const bf16x8*)(xrow);
    bf16x8 sa3 = *(const bf16x8*)(xrow + 32);

    int offv = 0, degv = 0;
    if (lane < 16) { offv = off[wbase + lane]; degv = deg[wbase + lane]; }

    int half = lane >> 5;        // node selector within pair
    int hl   = lane & 31;
    int fl   = hl & 15;          // feature quad: feats fl*4 .. fl*4+3
    int rg   = hl >> 4;          // row group 0..1
    int shb  = (half << 5) + rg; // shuffle base for own node's offsets
    unsigned flb = (unsigned)fl * 8u;          // byte offset within row
    const char* tb = (const char*)table;       // uniform 64-bit base

#define ACC(c) \
    a0  += __uint_as_float((c).x << 16); a1 += __uint_as_float((c).x & 0xFFFF0000u); \
    a2f += __uint_as_float((c).y << 16); a3f += __uint_as_float((c).y & 0xFFFF0000u);

    // ---- phase 1: 8 sequential pair aggregations ----
    for (int p = 0; p < 8; ++p) {
        int begA = __shfl(offv, 2 * p),     dgA = __shfl(degv, 2 * p);
        int begB = __shfl(offv, 2 * p + 1), dgB = __shfl(degv, 2 * p + 1);
        int pd = max((dgA + 7) & ~7, (dgB + 7) & ~7);   // shared padded length
        int myBeg = half ? begB : begA;
        float a0 = 0.f, a1 = 0.f, a2f = 0.f, a3f = 0.f;
        for (int k0 = 0; k0 < pd; k0 += 32) {
            int nb = adj[myBeg + k0 + hl];   // own node's byte offsets
            int lim = min(32, pd - k0);
            unsigned o0 = (unsigned)__shfl(nb, shb + 0) + flb;
            unsigned o1 = (unsigned)__shfl(nb, shb + 2) + flb;
            unsigned o2 = (unsigned)__shfl(nb, shb + 4) + flb;
            unsigned o3 = (unsigned)__shfl(nb, shb + 6) + flb;
            uint2 c0 = *(const uint2*)(tb + o0);
            uint2 c1 = *(const uint2*)(tb + o1);
            uint2 c2 = *(const uint2*)(tb + o2);
            uint2 c3 = *(const uint2*)(tb + o3);
            for (int tt = 8; tt < lim; tt += 8) {
                unsigned q0 = (unsigned)__shfl(nb, shb + tt + 0) + flb;
                unsigned q1 = (unsigned)__shfl(nb, shb + tt + 2) + flb;
                unsigned q2 = (unsigned)__shfl(nb, shb + tt + 4) + flb;
                unsigned q3 = (unsigned)__shfl(nb, shb + tt + 6) + flb;
                uint2 n0 = *(const uint2*)(tb + q0);
                uint2 n1 = *(const uint2*)(tb + q1);
                uint2 n2 = *(const uint2*)(tb + q2);
                uint2 n3 = *(const uint2*)(tb + q3);
                ACC(c0) ACC(c1) ACC(c2) ACC(c3)
                c0 = n0; c1 = n1; c2 = n2; c3 = n3;
            }
            ACC(c0) ACC(c1) ACC(c2) ACC(c3)
        }
        // combine the 2 row-groups of each half
        a0  += __shfl_xor(a0, 16);
        a1  += __shfl_xor(a1, 16);
        a2f += __shfl_xor(a2f, 16);
        a3f += __shfl_xor(a3f, 16);
        int mydg = half ? dgB : dgA;
        if (rg == 0) {   // lanes 0-15 write node 2p; lanes 32-47 write node 2p+1
            float inv = 1.0f / fmaxf((float)mydg, 1.0f);
            unsigned int lo = ((unsigned int)f2bf(a1 * inv) << 16) | f2bf(a0 * inv);
            unsigned int hi = ((unsigned int)f2bf(a3f * inv) << 16) | f2bf(a2f * inv);
            uint2 pk; pk.x = lo; pk.y = hi;
            *(uint2*)&sAgg[wave][2 * p + half][fl * 4] = pk;
        }
    }
#undef ACC
    // no __syncthreads: each wave reads only its own sAgg tile

    // ---- phase 2: MFMA update of the same 16 nodes ----
    bf16x8 a[4];
    a[0] = *(const bf16x8*)&sAgg[wave][row][g * 8];
    a[1] = *(const bf16x8*)&sAgg[wave][row][32 + g * 8];
    a[2] = sa2;
    a[3] = sa3;

#pragma unroll
    for (int ct = 0; ct < 4; ++ct) {
        int feat = ct * 16 + row;
        const u16* wrow = wt + feat * 128 + g * 8;
        f32x4 acc = {0.f, 0.f, 0.f, 0.f};
#pragma unroll
        for (int kb = 0; kb < 4; ++kb) {
            bf16x8 b = *(const bf16x8*)(wrow + kb * 32);
            acc = __builtin_amdgcn_mfma_f32_16x16x32_bf16(a[kb], b, acc, 0, 0, 0);
        }
        float s = sc_p[feat], h = sh_p[feat];
#pragma unroll
        for (int r = 0; r < 4; ++r) {
            int node = node0 + g * 4 + r;   // D: col=lane&15, row=(lane>>4)*4+r
            float v = fmaxf(acc[r] * s + h, 0.f);
            out[(size_t)node * H + feat] = f2bf(v);
        }
    }
}

// ================= MLP head (register-tiled fc1, LDS fc2, bf16 gathers) ========
__global__ __launch_bounds__(256) void mlp_kernel(
    const int* __restrict__ eli,
    const u16* __restrict__ xu16, const u16* __restrict__ xi16,
    const float* __restrict__ fc1w, const float* __restrict__ fc1b,
    const float* __restrict__ fc2w, const float* __restrict__ fc2b,
    float* __restrict__ out, int n)
{
    __shared__ float sW[32][68];
    __shared__ float sA[64][36];
    __shared__ float sH[64][68];
    __shared__ int   sid[128];
    __shared__ float sW2[256];
    int tid = threadIdx.x;
    int p0 = blockIdx.x * 64;
    if (tid < 128) {
        int p = p0 + (tid & 63);
        int side = tid >> 6;
        sid[tid] = (p < n) ? eli[side * NP + p] : -1;
    }
    sW2[tid] = fc2w[tid];
    __syncthreads();

    int jt = (tid & 15) * 4;
    int pt = (tid >> 4) * 4;
    float4 b4 = *(const float4*)&fc1b[jt];
    float acc[4][4];
#pragma unroll
    for (int i = 0; i < 4; ++i) {
        acc[i][0] = b4.x; acc[i][1] = b4.y; acc[i][2] = b4.z; acc[i][3] = b4.w;
    }

    for (int ch = 0; ch < 4; ++ch) {
        int k0 = ch * 32;
        const u16* tab = (ch < 2) ? xu16 : xi16;
        int idbase = (ch < 2) ? 0 : 64;
        int koff = (ch & 1) * 32;
        for (int idx = tid; idx < 64 * 16; idx += 256) {
            int r = idx >> 4, cp = idx & 15;
            int id = sid[idbase + r];
            unsigned int wv = (id >= 0)
                ? *(const unsigned int*)&tab[(size_t)id * H + koff + cp * 2] : 0u;
            sA[r][cp * 2]     = __uint_as_float(wv << 16);
            sA[r][cp * 2 + 1] = __uint_as_float(wv & 0xFFFF0000u);
        }
        for (int idx = tid; idx < 32 * 64; idx += 256) {
            int kk = idx >> 6, j = idx & 63;
            sW[kk][j] = fc1w[(k0 + kk) * 64 + j];
        }
        __syncthreads();
        for (int kk = 0; kk < 32; kk += 4) {
            float a[4][4];
#pragma unroll
            for (int i = 0; i < 4; ++i) {
                float4 t = *(const float4*)&sA[pt + i][kk];
                a[i][0] = t.x; a[i][1] = t.y; a[i][2] = t.z; a[i][3] = t.w;
            }
#pragma unroll
            for (int q = 0; q < 4; ++q) {
                float4 w = *(const float4*)&sW[kk + q][jt];
                float wv[4] = {w.x, w.y, w.z, w.w};
#pragma unroll
                for (int i = 0; i < 4; ++i)
#pragma unroll
                    for (int j = 0; j < 4; ++j)
                        acc[i][j] += a[i][q] * wv[j];
            }
        }
        __syncthreads();
    }

#pragma unroll
    for (int i = 0; i < 4; ++i)
#pragma unroll
        for (int j = 0; j < 4; ++j)
            sH[pt + i][jt + j] = fmaxf(acc[i][j], 0.f);
    __syncthreads();

    int pp = tid >> 2, c = tid & 3;
    float o = 0.f;
#pragma unroll
    for (int j = 0; j < 64; ++j) o += sH[pp][j] * sW2[j * 4 + c];
    int p = p0 + pp;
    if (p < n) out[(size_t)p * 4 + c] = o + fc2b[c];
}

extern "C" void kernel_launch(void* const* d_in, const int* in_sizes, int n_in,
                              void* d_out, int out_size, void* d_ws, size_t ws_size,
                              hipStream_t stream) {
    const int*   edge_index = (const int*)d_in[0];
    const int*   eli        = (const int*)d_in[1];
    const float* user_emb   = (const float*)d_in[2];
    const float* item_emb   = (const float*)d_in[3];
    const float* u_ll_w     = (const float*)d_in[4];
    const float* u_ll_b     = (const float*)d_in[5];
    const float* u_lr_w     = (const float*)d_in[6];
    const float* i_ll_w     = (const float*)d_in[7];
    const float* i_ll_b     = (const float*)d_in[8];
    const float* i_lr_w     = (const float*)d_in[9];
    const float* u_bn_g     = (const float*)d_in[10];
    const float* u_bn_b     = (const float*)d_in[11];
    const float* u_bn_m     = (const float*)d_in[12];
    const float* u_bn_v     = (const float*)d_in[13];
    const float* i_bn_g     = (const float*)d_in[14];
    const float* i_bn_b     = (const float*)d_in[15];
    const float* i_bn_m     = (const float*)d_in[16];
    const float* i_bn_v     = (const float*)d_in[17];
    const float* fc1_w      = (const float*)d_in[18];
    const float* fc1_b      = (const float*)d_in[19];
    const float* fc2_w      = (const float*)d_in[20];
    const float* fc2_b      = (const float*)d_in[21];
    float* out = (float*)d_out;

    const int* src = edge_index;
    const int* dst = edge_index + NE;

    // ---- workspace: 6 slots x 25.6 MB + adj 47.25 MB + off/deg 3.2 MB ≈ 205 MB
    //      (238 MB is the proven-safe ceiling) ----
    const size_t S = (size_t)NROW * H;   // elems per slot (incl. zero row)
    char* w = (char*)d_ws;
    u16* f1 = (u16*)w;          w += 6 * S * 2;
    int* adj    = (int*)w;      w += ((size_t)NB * CAP + 128) * 4;  // +128 overread pad
    int* off    = (int*)w;      w += (size_t)NN * 4;
    int* deg    = (int*)w;      w += (size_t)NN * 4;
    int* g_bcnt = (int*)w;      w += (size_t)NB * 4;
    u16* wcat   = (u16*)w;      w += (size_t)32768 * 2;   // [2][2][64][128] bf16
    float* scsh = (float*)w;    w += (size_t)512 * 4;     // [2][2][2][64] f32

    // Slot plan:
    //   s0/s1: emb16_u/i (prep -> L0 gather + self) -> fin16_u/i (L1 out -> mlp)
    //   s2/s3: staging (47.25 MB spans both; CSR build only)
    //   s4   : blkhist (1.6 MB head; dead after part2)
    //   s4/s5: xA16_u/i (L0 out; L1 gather + self)
    u16* emb16_u = f1 + 0 * S;
    u16* emb16_i = f1 + 1 * S;
    u16* fin16_u = f1 + 0 * S;
    u16* fin16_i = f1 + 1 * S;
    u16* xA16_u  = f1 + 4 * S;
    u16* xA16_i  = f1 + 5 * S;
    int* staging = (int*)(f1 + 2 * S);
    int* blkhist = (int*)(f1 + 4 * S);

    // ---- prep: part1 + cvt + wcvt in one dispatch ----
    prep_kernel<<<PBLOCKS + CVTB + WCVTB, 256, 0, stream>>>(
        src, dst, blkhist,
        (const float4*)user_emb, (const float4*)item_emb,
        (ushort4*)emb16_u, (ushort4*)emb16_i, f1,
        u_ll_w, u_lr_w, i_ll_w, i_lr_w, u_ll_b, i_ll_b,
        u_bn_g, u_bn_b, u_bn_m, u_bn_v,
        i_bn_g, i_bn_b, i_bn_m, i_bn_v, wcat, scsh);

    // ---- CSR build (no global atomics, no memsets, fixed-capacity buckets) ----
    colscan_kernel<<<NB, 256, 0, stream>>>(blkhist, g_bcnt);
    part2_kernel<<<PBLOCKS, 256, 0, stream>>>(src, dst, blkhist, staging);
    bucket_fill_kernel<<<NB, 256, 0, stream>>>(g_bcnt, staging, off, deg, adj);

    const int pu_blocks = (NN / 16) / 4;   // one wave per 16 nodes

    // ---- layer 0 (gather + self both from emb16) ----
    pull_update_kernel<<<pu_blocks, 256, 0, stream>>>(
        off, deg, adj, emb16_u, emb16_i, emb16_u, emb16_i,
        xA16_u, xA16_i, wcat, scsh);

    // ---- layer 1 (gather + self both from xA16) ----
    pull_update_kernel<<<pu_blocks, 256, 0, stream>>>(
        off, deg, adj, xA16_u, xA16_i, xA16_u, xA16_i,
        fin16_u, fin16_i, wcat + 16384, scsh + 256);

    // ---- MLP head ----
    mlp_kernel<<<(NP + 63) / 64, 256, 0, stream>>>(
        eli, fin16_u, fin16_i, fc1_w, fc1_b, fc2_w, fc2_b, out, NP);
}

// Round 19
// 545.680 us; speedup vs baseline: 1.0834x; 1.0024x over previous
//
#include <hip/hip_runtime.h>

#define NU 200000
#define NI 200000
#define NN 400000          // NU + NI (unified node space: users 0..NU-1, items NU..NN-1)
#define H 64
#define NE 4000000
#define NP 100000
#define EPSF 1e-5f

#define BSH 9              // nodes per bucket = 512
#define BNODES 512
#define NB ((NN + BNODES - 1) / BNODES)   // 782 buckets
#define CAP 15104          // per-bucket staging/adj capacity (padded mean ~13.3k)

#define PBLOCKS 512                          // partition blocks
#define EPB 7816                             // edges per block slice (mult of 8)

#define DUMMY 200000       // padded-slot neighbor id -> zeroed row in each table
#define NROW 200002        // table rows per slot (200000 real + zero row + align)

#define CVTB ((2 * (NU * H / 4) + 255) / 256)   // 25000 cvt blocks
#define WCVTB 128                                // wcvt blocks

typedef unsigned short u16;
typedef __attribute__((ext_vector_type(8))) short bf16x8;
typedef __attribute__((ext_vector_type(4))) float f32x4;

__device__ __forceinline__ u16 f2bf(float f) {
    unsigned int b = __float_as_uint(f);
    b += 0x7FFFu + ((b >> 16) & 1u);     // round-to-nearest-even
    return (u16)(b >> 16);
}

// ================= prep: part1 histogram + bf16 cvt + weight prep (one dispatch)
__global__ __launch_bounds__(256) void prep_kernel(
    const int* __restrict__ src, const int* __restrict__ dst,
    int* __restrict__ blkhist,
    const float4* __restrict__ inU, const float4* __restrict__ inI,
    ushort4* __restrict__ outU, ushort4* __restrict__ outI,
    u16* __restrict__ f1,
    const float* __restrict__ u_ll_w, const float* __restrict__ u_lr_w,
    const float* __restrict__ i_ll_w, const float* __restrict__ i_lr_w,
    const float* __restrict__ u_ll_b, const float* __restrict__ i_ll_b,
    const float* __restrict__ u_g, const float* __restrict__ u_b,
    const float* __restrict__ u_m, const float* __restrict__ u_v,
    const float* __restrict__ i_g, const float* __restrict__ i_b,
    const float* __restrict__ i_m, const float* __restrict__ i_v,
    u16* __restrict__ wcat, float* __restrict__ scsh)
{
    int bid = blockIdx.x, tid = threadIdx.x;
    if (bid < PBLOCKS) {
        // ---- part1: per-(bucket, block) entry counts ----
        __shared__ int hist[NB];
        for (int i = tid; i < NB; i += 256) hist[i] = 0;
        __syncthreads();
        int e0 = bid * EPB, e1 = min(NE, e0 + EPB);
        for (int e = e0 + tid * 4; e + 4 <= e1; e += 1024) {
            int4 s4 = *(const int4*)&src[e];
            int4 d4 = *(const int4*)&dst[e];
            atomicAdd(&hist[s4.x >> BSH], 1); atomicAdd(&hist[(NU + d4.x) >> BSH], 1);
            atomicAdd(&hist[s4.y >> BSH], 1); atomicAdd(&hist[(NU + d4.y) >> BSH], 1);
            atomicAdd(&hist[s4.z >> BSH], 1); atomicAdd(&hist[(NU + d4.z) >> BSH], 1);
            atomicAdd(&hist[s4.w >> BSH], 1); atomicAdd(&hist[(NU + d4.w) >> BSH], 1);
        }
        __syncthreads();
        for (int i = tid; i < NB; i += 256)
            blkhist[(size_t)i * PBLOCKS + bid] = hist[i];
    } else if (bid < PBLOCKS + CVTB) {
        // ---- cvt: f32 -> bf16 tables; block 0 also zeroes DUMMY rows 0,1,4,5 ----
        int cb = bid - PBLOCKS;
        if (cb == 0 && tid < 128) {
            const int sl[4] = {0, 1, 4, 5};
            int s = sl[tid >> 5], wd = tid & 31;
            unsigned int* p = (unsigned int*)(f1 + (size_t)s * NROW * H + (size_t)DUMMY * H);
            p[wd] = 0u;
        }
        const int n4 = NU * H / 4;
        int i = cb * 256 + tid;
        const float4* in;
        ushort4* out;
        if (i < n4) { in = inU; out = outU; }
        else        { in = inI; out = outI; i -= n4; if (i >= n4) return; }
        float4 v = in[i];
        ushort4 h;
        h.x = f2bf(v.x); h.y = f2bf(v.y); h.z = f2bf(v.z); h.w = f2bf(v.w);
        out[i] = h;
    } else {
        // ---- wcvt: stacked transposed bf16 weights + BN fold ----
        int idx = (bid - PBLOCKS - CVTB) * 256 + tid;
        if (idx < 32768) {
            int k = idx & 127, f = (idx >> 7) & 63, t = (idx >> 13) & 1, l = idx >> 14;
            const float* W = t ? (k < 64 ? i_ll_w : i_lr_w)
                               : (k < 64 ? u_ll_w : u_lr_w);
            wcat[idx] = f2bf(W[l * 4096 + (k & 63) * 64 + f]);
        }
        if (idx < 512) {
            int j = idx & 63, half = (idx >> 6) & 1, t = (idx >> 7) & 1, l = idx >> 8;
            const float *g = t ? i_g : u_g, *b = t ? i_b : u_b;
            const float *m = t ? i_m : u_m, *v = t ? i_v : u_v;
            const float *bl = t ? i_ll_b : u_ll_b;
            float sc = g[l * 64 + j] * rsqrtf(v[l * 64 + j] + EPSF);
            scsh[idx] = half ? (bl[l * 64 + j] - m[l * 64 + j]) * sc + b[l * 64 + j]
                             : sc;
        }
    }
}

// per-bucket exclusive scan over its PBLOCKS counts (in place); totals -> g_bcnt
__global__ __launch_bounds__(256) void colscan_kernel(
    int* __restrict__ blkhist, int* __restrict__ g_bcnt)
{
    __shared__ int s[256];
    int b = blockIdx.x, tid = threadIdx.x;
    int* col = blkhist + (size_t)b * PBLOCKS;
    int v0 = col[2 * tid], v1 = col[2 * tid + 1];
    int ps = v0 + v1;
    s[tid] = ps;
    __syncthreads();
    for (int d = 1; d < 256; d <<= 1) {
        int t = (tid >= d) ? s[tid - d] : 0;
        __syncthreads();
        s[tid] += t;
        __syncthreads();
    }
    int ex = s[tid] - ps;   // exclusive over pairs
    col[2 * tid] = ex;
    col[2 * tid + 1] = ex + v0;
    if (tid == 255) g_bcnt[b] = s[255];
}

// entry = (local_node << 18) | neighbor   (local<512 -> 9 bits, nbr<200000 -> 18 bits)
__global__ __launch_bounds__(256) void part2_kernel(
    const int* __restrict__ src, const int* __restrict__ dst,
    const int* __restrict__ blkhist, int* __restrict__ staging)
{
    __shared__ int cur[NB];
    int tid = threadIdx.x, blk = blockIdx.x;
    for (int i = tid; i < NB; i += 256)
        cur[i] = i * CAP + blkhist[(size_t)i * PBLOCKS + blk];
    __syncthreads();
    int e0 = blk * EPB, e1 = min(NE, e0 + EPB);
    for (int e = e0 + tid * 4; e + 4 <= e1; e += 1024) {
        int4 s4 = *(const int4*)&src[e];
        int4 d4 = *(const int4*)&dst[e];
        int sv[4] = {s4.x, s4.y, s4.z, s4.w};
        int dv[4] = {d4.x, d4.y, d4.z, d4.w};
#pragma unroll
        for (int q = 0; q < 4; ++q) {
            int s = sv[q], d = dv[q];
            int p1 = atomicAdd(&cur[s >> BSH], 1);
            staging[p1] = ((s & (BNODES - 1)) << 18) | d;
            int gn = NU + d;
            int p2 = atomicAdd(&cur[gn >> BSH], 1);
            staging[p2] = ((gn & (BNODES - 1)) << 18) | s;
        }
    }
}

// Per-bucket fill into pair-max-padded fixed-capacity adj: adj[b*CAP + i].
// Nodes (2t, 2t+1) are padded to the SAME 8-multiple length (max of the two);
// adj holds BYTE offsets (id*128) into the 128-B-row tables; pads -> DUMMY<<7.
__global__ __launch_bounds__(256) void bucket_fill_kernel(
    const int* __restrict__ g_bcnt, const int* __restrict__ staging,
    int* __restrict__ off, int* __restrict__ deg, int* __restrict__ adj)
{
    __shared__ int hist[BNODES];     // counts -> exclusive slot offsets (cursors)
    __shared__ int psum[256];
    __shared__ int adj_st[CAP];
    int tid = threadIdx.x;
    int b = blockIdx.x;
    int e0 = b * CAP;
    int cnt = g_bcnt[b];
    int node_base = b * BNODES;

    for (int i = tid; i < CAP; i += 256) adj_st[i] = DUMMY << 7;   // pad prefill
    hist[tid] = 0; hist[tid + 256] = 0;
    __syncthreads();
    for (int i = tid; i < cnt; i += 256)
        atomicAdd(&hist[staging[e0 + i] >> 18], 1);
    __syncthreads();

    int h0 = hist[2 * tid], h1 = hist[2 * tid + 1];
    int hp = max((h0 + 7) & ~7, (h1 + 7) & ~7);   // pair-max padded length
    psum[tid] = 2 * hp;
    __syncthreads();
    for (int d = 1; d < 256; d <<= 1) {
        int t = (tid >= d) ? psum[tid - d] : 0;
        __syncthreads();
        psum[tid] += t;
        __syncthreads();
    }
    int ex0 = psum[tid] - 2 * hp;
    int ex1 = ex0 + hp;
    int n0 = node_base + 2 * tid;
    if (n0 < NN)     { off[n0]     = e0 + ex0; deg[n0]     = h0; }
    if (n0 + 1 < NN) { off[n0 + 1] = e0 + ex1; deg[n0 + 1] = h1; }
    __syncthreads();
    hist[2 * tid] = ex0; hist[2 * tid + 1] = ex1;   // reuse as cursors
    __syncthreads();

    int ptotal = min(psum[255], CAP);   // statistically always < CAP

    for (int i = tid; i < cnt; i += 256) {
        int v = staging[e0 + i];
        int p = atomicAdd(&hist[v >> 18], 1);
        if (p < CAP) adj_st[p] = (v & 0x3FFFF) << 7;   // byte offset
    }
    __syncthreads();
    for (int i = tid; i < ptotal; i += 256)
        adj[(size_t)b * CAP + i] = adj_st[i];
}

// ================= fused pull + MFMA update ====================================
// One wave owns 16 nodes as 8 PAIRS: lanes 0-31 gather node 2p, lanes 32-63
// node 2p+1 (2 rows x 16 lanes). Pair-max padding -> no per-load clamps; adj
// holds byte offsets -> saddr loads. 2-deep pipeline, 4 loads per step.
__global__ __launch_bounds__(256) void pull_update_kernel(
    const int* __restrict__ off, const int* __restrict__ deg,
    const int* __restrict__ adj,
    const u16* __restrict__ xu16, const u16* __restrict__ xi16,   // gather tables
    const u16* __restrict__ selfU, const u16* __restrict__ selfI, // self-path rows
    u16* __restrict__ outU, u16* __restrict__ outI,
    const u16* __restrict__ wcat,    // this layer: [2 types][64 feat][128 k]
    const float* __restrict__ scsh)  // this layer: [2 types][2][64]
{
    __shared__ u16 sAgg[4][16][72];
    int tid = threadIdx.x;
    int wave = tid >> 6, lane = tid & 63;
    int gw = blockIdx.x * 4 + wave;            // global wave id, one per 16 nodes
    bool isU = gw < (NU / 16);
    int node0 = (isU ? gw : gw - NU / 16) * 16;
    const u16* table = isU ? xi16 : xu16;      // gather the OPPOSITE type
    const u16* selfx = isU ? selfU : selfI;
    u16* out         = isU ? outU : outI;
    const u16* wt      = wcat + (isU ? 0 : 64 * 128);
    const float* sc_p  = scsh + (isU ? 0 : 128);
    const float* sh_p  = sc_p + 64;
    int wbase = isU ? node0 : NU + node0;      // unified off/deg index

    // hoist self-path loads: in flight during the whole gather phase
    int row = lane & 15, g = lane >> 4;
    const u16* xrow = selfx + (size_t)(node0 + row) * H + g * 8;
    bf16x8 sa2 = *(const bf16x8*)(xrow);
    bf16x8 sa3 = *(const bf16x8*)(xrow + 32);

    int offv = 0, degv = 0;
    if (lane < 16) { offv = off[wbase + lane]; degv = deg[wbase + lane]; }

    int half = lane >> 5;        // node selector within pair
    int hl   = lane & 31;
    int fl   = hl & 15;          // feature quad: feats fl*4 .. fl*4+3
    int rg   = hl >> 4;          // row group 0..1
    int shb  = (half << 5) + rg; // shuffle base for own node's offsets
    unsigned flb = (unsigned)fl * 8u;          // byte offset within row
    const char* tb = (const char*)table;       // uniform 64-bit base

#define ACC(c) \
    a0  += __uint_as_float((c).x << 16); a1 += __uint_as_float((c).x & 0xFFFF0000u); \
    a2f += __uint_as_float((c).y << 16); a3f += __uint_as_float((c).y & 0xFFFF0000u);

    // ---- phase 1: 8 sequential pair aggregations ----
    for (int p = 0; p < 8; ++p) {
        int begA = __shfl(offv, 2 * p),     dgA = __shfl(degv, 2 * p);
        int begB = __shfl(offv, 2 * p + 1), dgB = __shfl(degv, 2 * p + 1);
        int pd = max((dgA + 7) & ~7, (dgB + 7) & ~7);   // shared padded length
        int myBeg = half ? begB : begA;
        float a0 = 0.f, a1 = 0.f, a2f = 0.f, a3f = 0.f;
        for (int k0 = 0; k0 < pd; k0 += 32) {
            int nb = adj[myBeg + k0 + hl];   // own node's byte offsets
            int lim = min(32, pd - k0);
            unsigned o0 = (unsigned)__shfl(nb, shb + 0) + flb;
            unsigned o1 = (unsigned)__shfl(nb, shb + 2) + flb;
            unsigned o2 = (unsigned)__shfl(nb, shb + 4) + flb;
            unsigned o3 = (unsigned)__shfl(nb, shb + 6) + flb;
            uint2 c0 = *(const uint2*)(tb + o0);
            uint2 c1 = *(const uint2*)(tb + o1);
            uint2 c2 = *(const uint2*)(tb + o2);
            uint2 c3 = *(const uint2*)(tb + o3);
            for (int tt = 8; tt < lim; tt += 8) {
                unsigned q0 = (unsigned)__shfl(nb, shb + tt + 0) + flb;
                unsigned q1 = (unsigned)__shfl(nb, shb + tt + 2) + flb;
                unsigned q2 = (unsigned)__shfl(nb, shb + tt + 4) + flb;
                unsigned q3 = (unsigned)__shfl(nb, shb + tt + 6) + flb;
                uint2 n0 = *(const uint2*)(tb + q0);
                uint2 n1 = *(const uint2*)(tb + q1);
                uint2 n2 = *(const uint2*)(tb + q2);
                uint2 n3 = *(const uint2*)(tb + q3);
                ACC(c0) ACC(c1) ACC(c2) ACC(c3)
                c0 = n0; c1 = n1; c2 = n2; c3 = n3;
            }
            ACC(c0) ACC(c1) ACC(c2) ACC(c3)
        }
        // combine the 2 row-groups of each half
        a0  += __shfl_xor(a0, 16);
        a1  += __shfl_xor(a1, 16);
        a2f += __shfl_xor(a2f, 16);
        a3f += __shfl_xor(a3f, 16);
        int mydg = half ? dgB : dgA;
        if (rg == 0) {   // lanes 0-15 write node 2p; lanes 32-47 write node 2p+1
            float inv = 1.0f / fmaxf((float)mydg, 1.0f);
            unsigned int lo = ((unsigned int)f2bf(a1 * inv) << 16) | f2bf(a0 * inv);
            unsigned int hi = ((unsigned int)f2bf(a3f * inv) << 16) | f2bf(a2f * inv);
            uint2 pk; pk.x = lo; pk.y = hi;
            *(uint2*)&sAgg[wave][2 * p + half][fl * 4] = pk;
        }
    }
#undef ACC
    // no __syncthreads: each wave reads only its own sAgg tile

    // ---- phase 2: MFMA update of the same 16 nodes ----
    bf16x8 a[4];
    a[0] = *(const bf16x8*)&sAgg[wave][row][g * 8];
    a[1] = *(const bf16x8*)&sAgg[wave][row][32 + g * 8];
    a[2] = sa2;
    a[3] = sa3;

#pragma unroll
    for (int ct = 0; ct < 4; ++ct) {
        int feat = ct * 16 + row;
        const u16* wrow = wt + feat * 128 + g * 8;
        f32x4 acc = {0.f, 0.f, 0.f, 0.f};
#pragma unroll
        for (int kb = 0; kb < 4; ++kb) {
            bf16x8 b = *(const bf16x8*)(wrow + kb * 32);
            acc = __builtin_amdgcn_mfma_f32_16x16x32_bf16(a[kb], b, acc, 0, 0, 0);
        }
        float s = sc_p[feat], h = sh_p[feat];
#pragma unroll
        for (int r = 0; r < 4; ++r) {
            int node = node0 + g * 4 + r;   // D: col=lane&15, row=(lane>>4)*4+r
            float v = fmaxf(acc[r] * s + h, 0.f);
            out[(size_t)node * H + feat] = f2bf(v);
        }
    }
}

// ================= MLP head (register-tiled fc1, LDS fc2, bf16 gathers) ========
__global__ __launch_bounds__(256) void mlp_kernel(
    const int* __restrict__ eli,
    const u16* __restrict__ xu16, const u16* __restrict__ xi16,
    const float* __restrict__ fc1w, const float* __restrict__ fc1b,
    const float* __restrict__ fc2w, const float* __restrict__ fc2b,
    float* __restrict__ out, int n)
{
    __shared__ float sW[32][68];
    __shared__ float sA[64][36];
    __shared__ float sH[64][68];
    __shared__ int   sid[128];
    __shared__ float sW2[256];
    int tid = threadIdx.x;
    int p0 = blockIdx.x * 64;
    if (tid < 128) {
        int p = p0 + (tid & 63);
        int side = tid >> 6;
        sid[tid] = (p < n) ? eli[side * NP + p] : -1;
    }
    sW2[tid] = fc2w[tid];
    __syncthreads();

    int jt = (tid & 15) * 4;
    int pt = (tid >> 4) * 4;
    float4 b4 = *(const float4*)&fc1b[jt];
    float acc[4][4];
#pragma unroll
    for (int i = 0; i < 4; ++i) {
        acc[i][0] = b4.x; acc[i][1] = b4.y; acc[i][2] = b4.z; acc[i][3] = b4.w;
    }

    for (int ch = 0; ch < 4; ++ch) {
        int k0 = ch * 32;
        const u16* tab = (ch < 2) ? xu16 : xi16;
        int idbase = (ch < 2) ? 0 : 64;
        int koff = (ch & 1) * 32;
        for (int idx = tid; idx < 64 * 16; idx += 256) {
            int r = idx >> 4, cp = idx & 15;
            int id = sid[idbase + r];
            unsigned int wv = (id >= 0)
                ? *(const unsigned int*)&tab[(size_t)id * H + koff + cp * 2] : 0u;
            sA[r][cp * 2]     = __uint_as_float(wv << 16);
            sA[r][cp * 2 + 1] = __uint_as_float(wv & 0xFFFF0000u);
        }
        for (int idx = tid; idx < 32 * 64; idx += 256) {
            int kk = idx >> 6, j = idx & 63;
            sW[kk][j] = fc1w[(k0 + kk) * 64 + j];
        }
        __syncthreads();
        for (int kk = 0; kk < 32; kk += 4) {
            float a[4][4];
#pragma unroll
            for (int i = 0; i < 4; ++i) {
                float4 t = *(const float4*)&sA[pt + i][kk];
                a[i][0] = t.x; a[i][1] = t.y; a[i][2] = t.z; a[i][3] = t.w;
            }
#pragma unroll
            for (int q = 0; q < 4; ++q) {
                float4 w = *(const float4*)&sW[kk + q][jt];
                float wv[4] = {w.x, w.y, w.z, w.w};
#pragma unroll
                for (int i = 0; i < 4; ++i)
#pragma unroll
                    for (int j = 0; j < 4; ++j)
                        acc[i][j] += a[i][q] * wv[j];
            }
        }
        __syncthreads();
    }

#pragma unroll
    for (int i = 0; i < 4; ++i)
#pragma unroll
        for (int j = 0; j < 4; ++j)
            sH[pt + i][jt + j] = fmaxf(acc[i][j], 0.f);
    __syncthreads();

    int pp = tid >> 2, c = tid & 3;
    float o = 0.f;
#pragma unroll
    for (int j = 0; j < 64; ++j) o += sH[pp][j] * sW2[j * 4 + c];
    int p = p0 + pp;
    if (p < n) out[(size_t)p * 4 + c] = o + fc2b[c];
}

extern "C" void kernel_launch(void* const* d_in, const int* in_sizes, int n_in,
                              void* d_out, int out_size, void* d_ws, size_t ws_size,
                              hipStream_t stream) {
    const int*   edge_index = (const int*)d_in[0];
    const int*   eli        = (const int*)d_in[1];
    const float* user_emb   = (const float*)d_in[2];
    const float* item_emb   = (const float*)d_in[3];
    const float* u_ll_w     = (const float*)d_in[4];
    const float* u_ll_b     = (const float*)d_in[5];
    const float* u_lr_w     = (const float*)d_in[6];
    const float* i_ll_w     = (const float*)d_in[7];
    const float* i_ll_b     = (const float*)d_in[8];
    const float* i_lr_w     = (const float*)d_in[9];
    const float* u_bn_g     = (const float*)d_in[10];
    const float* u_bn_b     = (const float*)d_in[11];
    const float* u_bn_m     = (const float*)d_in[12];
    const float* u_bn_v     = (const float*)d_in[13];
    const float* i_bn_g     = (const float*)d_in[14];
    const float* i_bn_b     = (const float*)d_in[15];
    const float* i_bn_m     = (const float*)d_in[16];
    const float* i_bn_v     = (const float*)d_in[17];
    const float* fc1_w      = (const float*)d_in[18];
    const float* fc1_b      = (const float*)d_in[19];
    const float* fc2_w      = (const float*)d_in[20];
    const float* fc2_b      = (const float*)d_in[21];
    float* out = (float*)d_out;

    const int* src = edge_index;
    const int* dst = edge_index + NE;

    // ---- workspace: 6 slots x 25.6 MB + adj 47.25 MB + off/deg 3.2 MB ≈ 205 MB
    //      (238 MB is the proven-safe ceiling) ----
    const size_t S = (size_t)NROW * H;   // elems per slot (incl. zero row)
    char* w = (char*)d_ws;
    u16* f1 = (u16*)w;          w += 6 * S * 2;
    int* adj    = (int*)w;      w += ((size_t)NB * CAP + 128) * 4;  // +128 overread pad
    int* off    = (int*)w;      w += (size_t)NN * 4;
    int* deg    = (int*)w;      w += (size_t)NN * 4;
    int* g_bcnt = (int*)w;      w += (size_t)NB * 4;
    u16* wcat   = (u16*)w;      w += (size_t)32768 * 2;   // [2][2][64][128] bf16
    float* scsh = (float*)w;    w += (size_t)512 * 4;     // [2][2][2][64] f32

    // Slot plan:
    //   s0/s1: emb16_u/i (prep -> L0 gather + self) -> fin16_u/i (L1 out -> mlp)
    //   s2/s3: staging (47.25 MB spans both; CSR build only)
    //   s4   : blkhist (1.6 MB head; dead after part2)
    //   s4/s5: xA16_u/i (L0 out; L1 gather + self)
    u16* emb16_u = f1 + 0 * S;
    u16* emb16_i = f1 + 1 * S;
    u16* fin16_u = f1 + 0 * S;
    u16* fin16_i = f1 + 1 * S;
    u16* xA16_u  = f1 + 4 * S;
    u16* xA16_i  = f1 + 5 * S;
    int* staging = (int*)(f1 + 2 * S);
    int* blkhist = (int*)(f1 + 4 * S);

    // ---- prep: part1 + cvt + wcvt in one dispatch ----
    prep_kernel<<<PBLOCKS + CVTB + WCVTB, 256, 0, stream>>>(
        src, dst, blkhist,
        (const float4*)user_emb, (const float4*)item_emb,
        (ushort4*)emb16_u, (ushort4*)emb16_i, f1,
        u_ll_w, u_lr_w, i_ll_w, i_lr_w, u_ll_b, i_ll_b,
        u_bn_g, u_bn_b, u_bn_m, u_bn_v,
        i_bn_g, i_bn_b, i_bn_m, i_bn_v, wcat, scsh);

    // ---- CSR build (no global atomics, no memsets, fixed-capacity buckets) ----
    colscan_kernel<<<NB, 256, 0, stream>>>(blkhist, g_bcnt);
    part2_kernel<<<PBLOCKS, 256, 0, stream>>>(src, dst, blkhist, staging);
    bucket_fill_kernel<<<NB, 256, 0, stream>>>(g_bcnt, staging, off, deg, adj);

    const int pu_blocks = (NN / 16) / 4;   // one wave per 16 nodes

    // ---- layer 0 (gather + self both from emb16) ----
    pull_update_kernel<<<pu_blocks, 256, 0, stream>>>(
        off, deg, adj, emb16_u, emb16_i, emb16_u, emb16_i,
        xA16_u, xA16_i, wcat, scsh);

    // ---- layer 1 (gather + self both from xA16) ----
    pull_update_kernel<<<pu_blocks, 256, 0, stream>>>(
        off, deg, adj, xA16_u, xA16_i, xA16_u, xA16_i,
        fin16_u, fin16_i, wcat + 16384, scsh + 256);

    // ---- MLP head ----
    mlp_kernel<<<(NP + 63) / 64, 256, 0, stream>>>(
        eli, fin16_u, fin16_i, fc1_w, fc1_b, fc2_w, fc2_b, out, NP);
}